// Round 10
// baseline (41.223 us; speedup 1.0000x reference)
//
#include <hip/hip_runtime.h>

// Problem: B=4, N=384, DX=2, DR=128, H=128, DOUT=64
// out[b,n,m,o] = relu( (x_ctx[b,n]-x_ctx[b,m]) @ W1[0:2] + r[b] @ W1[2:130] + b1 ) @ W2 + b2
//
// Round-10: R4 skeleton + SOFTWARE-PIPELINED 3-BANK EPILOGUE.
// Why R9 failed to test the latency theory: full unroll does not force
// distinct store-data registers -- iter i's rowv dies before iter i+1's is
// born, so regalloc reuses the same 4 VGPRs and the store->reload WAR stays
// ~1 body (~700cy) < loaded store latency (~1500-2000cy) -> ~45% stall ->
// 3.8 TB/s (R4==R5==R9==40.5us).
// Fix: bodies are  { store tile t-1 from bank X ; compute tile t ; ds_read
// into bank Y }  with 3 rotating banks. X and Y are simultaneously live ->
// guaranteed distinct registers; bank X is redefined ~2.7 bodies (~1900cy)
// after its stores issue; ~8KB/wave stores continuously in flight
// (~64KB/CU >> 23KB Little's-law need for 6.7 TB/s).
// Kept from R4 (evidence): contiguous 1KB/wave bursts via per-wave LDS
// transpose (R6 strided=3.0TB/s, R8 scalarized=1.4TB/s+RFO), plain cached
// stores (R7 NT=2.1TB/s), no inline asm (R8), single barrier, grid 1536.

typedef __attribute__((ext_vector_type(8))) __bf16 bf16x8;
typedef __attribute__((ext_vector_type(4))) float f32x4;

#define B_    4
#define N_    384
#define H_    128
#define DOUT_ 64

__global__ __launch_bounds__(256, 2) void te_fused(
    const float* __restrict__ r, const float* __restrict__ xctx,
    const float* __restrict__ W1, const float* __restrict__ b1,
    const float* __restrict__ W2, const float* __restrict__ b2,
    float* __restrict__ out)
{
    __shared__ __align__(16) float xs[N_ * 2];        // 3 KB  x_ctx[b]
    __shared__ __align__(16) float cpart[2][H_];      // 1 KB  c partials
    __shared__ __align__(16) float tbuf[4][16][64];   // 16 KB per-wave transpose

    const int tid  = threadIdx.x;
    const int wave = tid >> 6, lane = tid & 63;
    const int g = lane >> 4, rl = lane & 15;

    const int bid = blockIdx.x;
    const int b = bid / N_, n = bid - b * N_;

    // ---- prologue: c partial reduction (all 256 threads) ----
    {
        const int k = tid & 127, dh = tid >> 7;
        float acc = dh ? 0.f : b1[k];
        const float* wc = W1 + (2 + dh * 64) * H_ + k;
        const float* rb = r + b * 128 + dh * 64;
        #pragma unroll 8
        for (int d = 0; d < 64; ++d) acc = fmaf(rb[d], wc[d * H_], acc);
        cpart[dh][k] = acc;
    }
    // ---- stage x_ctx[b] (192 threads x 16 B) ----
    if (tid < 192)
        *reinterpret_cast<f32x4*>(&xs[tid * 4]) =
            *reinterpret_cast<const f32x4*>(xctx + b * (N_ * 2) + tid * 4);

    // ---- W2^T fragments: w2f[rt][ks][jj] = bf16(W2[kk][rt*16+rl]),
    //      kk = ks*32 + (jj>=4)*16 + g*4 + (jj&3)  (scalar gathers, L2-hit) ----
    bf16x8 w2f[4][4];
    #pragma unroll
    for (int rt = 0; rt < 4; ++rt) {
        const float* wp = W2 + rt * 16 + rl;   // + kk*64
        #pragma unroll
        for (int ks = 0; ks < 4; ++ks)
            #pragma unroll
            for (int jj = 0; jj < 8; ++jj) {
                const int kk = ks * 32 + ((jj >> 2) << 4) + (g << 2) + (jj & 3);
                w2f[rt][ks][jj] = (__bf16)wp[kk * DOUT_];
            }
    }

    // ---- W1 row-0/row-1 fragments + b2 fragments ----
    f32x4 w1a[4][2], w1b[4][2], cf[4][2], b2f[4];
    #pragma unroll
    for (int ks = 0; ks < 4; ++ks)
        #pragma unroll
        for (int hh = 0; hh < 2; ++hh) {
            const int kk = ks * 32 + hh * 16 + (g << 2);
            w1a[ks][hh] = *reinterpret_cast<const f32x4*>(W1 + kk);
            w1b[ks][hh] = *reinterpret_cast<const f32x4*>(W1 + H_ + kk);
        }
    #pragma unroll
    for (int rt = 0; rt < 4; ++rt)
        b2f[rt] = *reinterpret_cast<const f32x4*>(b2 + rt * 16 + (g << 2));

    __syncthreads();   // xs + cpart ready (only barrier in the kernel)

    // ---- c fragments ----
    #pragma unroll
    for (int ks = 0; ks < 4; ++ks)
        #pragma unroll
        for (int hh = 0; hh < 2; ++hh) {
            const int kk = ks * 32 + hh * 16 + (g << 2);
            cf[ks][hh] = *reinterpret_cast<const f32x4*>(&cpart[0][kk]) +
                         *reinterpret_cast<const f32x4*>(&cpart[1][kk]);
        }

    const float x0n = xs[2 * n], x1n = xs[2 * n + 1];
    float* tb = &tbuf[wave][0][0];
    const int cb2 = lane & 15;
    float* const outn = out + ((size_t)(b * N_ + n)) * N_ * DOUT_;

    // compute tile t: h-preact, 16 MFMA, LDS transpose write, readback into bank
    auto compute_tile = [&](int t, f32x4* bank) {
        const int mbase = wave * 96 + t * 16;
        const int m = mbase + rl;
        const float dx0 = x0n - xs[2 * m];
        const float dx1 = x1n - xs[2 * m + 1];

        bf16x8 hf[4];
        #pragma unroll
        for (int ks = 0; ks < 4; ++ks)
            #pragma unroll
            for (int hh = 0; hh < 2; ++hh)
                #pragma unroll
                for (int j = 0; j < 4; ++j) {
                    float hp = fmaf(dx1, w1b[ks][hh][j],
                               fmaf(dx0, w1a[ks][hh][j], cf[ks][hh][j]));
                    hf[ks][hh * 4 + j] = (__bf16)(hp > 0.f ? hp : 0.f);
                }

        f32x4 acc[4];
        #pragma unroll
        for (int rt = 0; rt < 4; ++rt) acc[rt] = b2f[rt];
        #pragma unroll
        for (int ks = 0; ks < 4; ++ks)
            #pragma unroll
            for (int rt = 0; rt < 4; ++rt)
                acc[rt] = __builtin_amdgcn_mfma_f32_16x16x32_bf16(w2f[rt][ks], hf[ks], acc[rt], 0, 0, 0);

        // per-wave LDS transpose write (XOR block swizzle, bank-uniform);
        // same-wave in-order DS pipe makes write->read safe without barrier
        // (validated by R4 passing).
        #pragma unroll
        for (int rt = 0; rt < 4; ++rt) {
            const int cblk = ((rt << 2) | g) ^ rl;
            *reinterpret_cast<f32x4*>(tb + (rl << 6) + (cblk << 2)) = acc[rt];
        }
        #pragma unroll
        for (int q = 0; q < 4; ++q) {
            const int mm = (lane >> 4) | (q << 2);
            bank[q] = *reinterpret_cast<const f32x4*>(tb + (mm << 6) + ((cb2 ^ mm) << 2));
        }
    };

    // store tile t from bank: 4 x 1KB fully-contiguous cached stores
    auto store_tile = [&](int t, const f32x4* bank) {
        float* onp = outn + (size_t)(wave * 96 + t * 16) * DOUT_;
        #pragma unroll
        for (int q = 0; q < 4; ++q) {
            const int mm = (lane >> 4) | (q << 2);
            *reinterpret_cast<f32x4*>(onp + mm * DOUT_ + (cb2 << 2)) = bank[q];
        }
    };

    // 3-bank pipelined schedule: stores of tile t-1 issue at top of body t;
    // a bank's registers are redefined ~2.7 bodies after its stores issue.
    f32x4 rv0[4], rv1[4], rv2[4];
    compute_tile(0, rv0);
    store_tile(0, rv0);  compute_tile(1, rv1);
    store_tile(1, rv1);  compute_tile(2, rv2);
    store_tile(2, rv2);  compute_tile(3, rv0);
    store_tile(3, rv0);  compute_tile(4, rv1);
    store_tile(4, rv1);  compute_tile(5, rv2);
    store_tile(5, rv2);
}

extern "C" void kernel_launch(void* const* d_in, const int* in_sizes, int n_in,
                              void* d_out, int out_size, void* d_ws, size_t ws_size,
                              hipStream_t stream)
{
    const float* r    = (const float*)d_in[0];
    const float* xctx = (const float*)d_in[1];
    // d_in[2] = y_ctx (unused), d_in[3] = x_trg (unused)
    const float* W1 = (const float*)d_in[4];
    const float* b1 = (const float*)d_in[5];
    const float* W2 = (const float*)d_in[6];
    const float* b2 = (const float*)d_in[7];
    float* out = (float*)d_out;

    hipLaunchKernelGGL(te_fused, dim3(B_ * N_), dim3(256), 0, stream,
                       r, xctx, W1, b1, W2, b2, out);
}

// Round 11
// 32.947 us; speedup vs baseline: 1.2512x; 1.2512x over previous
//
#include <hip/hip_runtime.h>

// Problem: B=4, N=384, DX=2, DR=128, H=128, DOUT=64
// out[b,n,m,o] = relu( (x_ctx[b,n]-x_ctx[b,m]) @ W1[0:2] + r[b] @ W1[2:130] + b1 ) @ W2 + b2
//
// Round-11: PERSISTENT 1-BLOCK/CU experiment (grid 256, 4 waves, 6 rows per
// block; 384%6==0 so a block's rows stay within one batch b).
// Rationale: R4(drain/iter)==R5(barrier/iter)==R9(full unroll)==R10(3-bank
// SWP) == 40.5-41.2us == ~4.0 TB/s across two occupancy levels -> the wall
// is schedule-independent. This round tests occupancy-independence at the
// extreme (4 waves/CU) with a byte-identical store pattern, amortizes the
// prologue 6x, and -- if it lands >=88us -- finally pushes te_fused into
// the rocprof top-5 so FETCH_SIZE can confirm/kill the RFO theory.
// Pre-committed readout: ~40us -> wall confirmed, revert to R4 + declare;
// >=60us -> occupancy matters (and maybe counters); <36us -> prologue was
// the residual, keep.
// Kept from R4 (evidence): per-wave LDS transpose -> 4x1KB contiguous
// cached stores (R6 strided=3.0TB/s, R7 NT=2.1TB/s, R8 asm=RFO blowup),
// no inline asm, single barrier.

typedef __attribute__((ext_vector_type(8))) __bf16 bf16x8;
typedef __attribute__((ext_vector_type(4))) float f32x4;

#define B_    4
#define N_    384
#define H_    128
#define DOUT_ 64

__global__ __launch_bounds__(256, 1) void te_fused(
    const float* __restrict__ r, const float* __restrict__ xctx,
    const float* __restrict__ W1, const float* __restrict__ b1,
    const float* __restrict__ W2, const float* __restrict__ b2,
    float* __restrict__ out)
{
    __shared__ __align__(16) float xs[N_ * 2];        // 3 KB  x_ctx[b]
    __shared__ __align__(16) float cpart[2][H_];      // 1 KB  c partials
    __shared__ __align__(16) float tbuf[4][16][64];   // 16 KB per-wave transpose

    const int tid  = threadIdx.x;
    const int wave = tid >> 6, lane = tid & 63;
    const int g = lane >> 4, rl = lane & 15;

    const int bid  = blockIdx.x;       // 0..255
    const int row0 = bid * 6;          // first global row; all 6 share b
    const int b    = row0 / N_;
    const int n0   = row0 - b * N_;

    // ---- prologue: c partial reduction (all 256 threads) ----
    {
        const int k = tid & 127, dh = tid >> 7;
        float acc = dh ? 0.f : b1[k];
        const float* wc = W1 + (2 + dh * 64) * H_ + k;
        const float* rb = r + b * 128 + dh * 64;
        #pragma unroll 8
        for (int d = 0; d < 64; ++d) acc = fmaf(rb[d], wc[d * H_], acc);
        cpart[dh][k] = acc;
    }
    // ---- stage x_ctx[b] (192 threads x 16 B) ----
    if (tid < 192)
        *reinterpret_cast<f32x4*>(&xs[tid * 4]) =
            *reinterpret_cast<const f32x4*>(xctx + b * (N_ * 2) + tid * 4);

    // ---- W2^T fragments: w2f[rt][ks][jj] = bf16(W2[kk][rt*16+rl]),
    //      kk = ks*32 + (jj>=4)*16 + g*4 + (jj&3)  (scalar gathers, L2-hit) ----
    bf16x8 w2f[4][4];
    #pragma unroll
    for (int rt = 0; rt < 4; ++rt) {
        const float* wp = W2 + rt * 16 + rl;   // + kk*64
        #pragma unroll
        for (int ks = 0; ks < 4; ++ks)
            #pragma unroll
            for (int jj = 0; jj < 8; ++jj) {
                const int kk = ks * 32 + ((jj >> 2) << 4) + (g << 2) + (jj & 3);
                w2f[rt][ks][jj] = (__bf16)wp[kk * DOUT_];
            }
    }

    // ---- W1 row-0/row-1 fragments + b2 fragments ----
    f32x4 w1a[4][2], w1b[4][2], cf[4][2], b2f[4];
    #pragma unroll
    for (int ks = 0; ks < 4; ++ks)
        #pragma unroll
        for (int hh = 0; hh < 2; ++hh) {
            const int kk = ks * 32 + hh * 16 + (g << 2);
            w1a[ks][hh] = *reinterpret_cast<const f32x4*>(W1 + kk);
            w1b[ks][hh] = *reinterpret_cast<const f32x4*>(W1 + H_ + kk);
        }
    #pragma unroll
    for (int rt = 0; rt < 4; ++rt)
        b2f[rt] = *reinterpret_cast<const f32x4*>(b2 + rt * 16 + (g << 2));

    __syncthreads();   // xs + cpart ready (only barrier in the kernel)

    // ---- c fragments ----
    #pragma unroll
    for (int ks = 0; ks < 4; ++ks)
        #pragma unroll
        for (int hh = 0; hh < 2; ++hh) {
            const int kk = ks * 32 + hh * 16 + (g << 2);
            cf[ks][hh] = *reinterpret_cast<const f32x4*>(&cpart[0][kk]) +
                         *reinterpret_cast<const f32x4*>(&cpart[1][kk]);
        }

    float* tb = &tbuf[wave][0][0];
    const int cb2 = lane & 15;

    // ---- 6 rows x 6 m-tiles; store pattern identical to R4 ----
    for (int rr = 0; rr < 6; ++rr) {
        const int n = n0 + rr;
        const float x0n = xs[2 * n], x1n = xs[2 * n + 1];
        float* const outn = out + ((size_t)(row0 + rr)) * N_ * DOUT_;

        for (int t = 0; t < 6; ++t) {
            const int mbase = wave * 96 + t * 16;
            const int m = mbase + rl;
            const float dx0 = x0n - xs[2 * m];
            const float dx1 = x1n - xs[2 * m + 1];

            bf16x8 hf[4];
            #pragma unroll
            for (int ks = 0; ks < 4; ++ks)
                #pragma unroll
                for (int hh = 0; hh < 2; ++hh)
                    #pragma unroll
                    for (int j = 0; j < 4; ++j) {
                        float hp = fmaf(dx1, w1b[ks][hh][j],
                                   fmaf(dx0, w1a[ks][hh][j], cf[ks][hh][j]));
                        hf[ks][hh * 4 + j] = (__bf16)(hp > 0.f ? hp : 0.f);
                    }

            f32x4 acc[4];
            #pragma unroll
            for (int rt = 0; rt < 4; ++rt) acc[rt] = b2f[rt];
            #pragma unroll
            for (int ks = 0; ks < 4; ++ks)
                #pragma unroll
                for (int rt = 0; rt < 4; ++rt)
                    acc[rt] = __builtin_amdgcn_mfma_f32_16x16x32_bf16(w2f[rt][ks], hf[ks], acc[rt], 0, 0, 0);

            // per-wave LDS transpose (XOR block swizzle) -> 4 x 1KB contiguous stores
            #pragma unroll
            for (int rt = 0; rt < 4; ++rt) {
                const int cblk = ((rt << 2) | g) ^ rl;
                *reinterpret_cast<f32x4*>(tb + (rl << 6) + (cblk << 2)) = acc[rt];
            }
            float* onp = outn + (size_t)mbase * DOUT_;
            #pragma unroll
            for (int q = 0; q < 4; ++q) {
                const int mm = (lane >> 4) | (q << 2);
                f32x4 rowv = *reinterpret_cast<const f32x4*>(tb + (mm << 6) + ((cb2 ^ mm) << 2));
                *reinterpret_cast<f32x4*>(onp + mm * DOUT_ + (cb2 << 2)) = rowv;
            }
        }
    }
}

extern "C" void kernel_launch(void* const* d_in, const int* in_sizes, int n_in,
                              void* d_out, int out_size, void* d_ws, size_t ws_size,
                              hipStream_t stream)
{
    const float* r    = (const float*)d_in[0];
    const float* xctx = (const float*)d_in[1];
    // d_in[2] = y_ctx (unused), d_in[3] = x_trg (unused)
    const float* W1 = (const float*)d_in[4];
    const float* b1 = (const float*)d_in[5];
    const float* W2 = (const float*)d_in[6];
    const float* b2 = (const float*)d_in[7];
    float* out = (float*)d_out;

    hipLaunchKernelGGL(te_fused, dim3(256), dim3(256), 0, stream,
                       r, xctx, W1, b1, W2, b2, out);
}